// Round 19
// baseline (39.106 us; speedup 1.0000x reference)
//
#include <hip/hip_runtime.h>
#include <stdint.h>

#define NB    64
#define IN    512
#define OUT   512
#define NTOK  512
#define NSEL  1024      // NTOK*K
#define MCAP  32        // token slots per pass
#define KH    256       // K rows per block (half)  -- R12 sweet spot
#define XSTR  264       // bf16 per X row (256 + 8 pad)
#define ELCAP 96

typedef __attribute__((ext_vector_type(8))) short bf16x8;
typedef __attribute__((ext_vector_type(4))) float f32x4;

// v_cvt_pk_bf16_f32: d[15:0]=bf16(lo), d[31:16]=bf16(hi), RNE (verified R14)
__device__ __forceinline__ uint32_t cvt_pk_bf16(float lo, float hi) {
    uint32_t r;
    asm("v_cvt_pk_bf16_f32 %0, %1, %2" : "=v"(r) : "v"(lo), "v"(hi));
    return r;
}

// Block = (bank, 64-col tile, 256-row K-half): 1024 blocks, 256 thr = 4 waves.
// R18 + fully-unrolled K loop: compiler may hoist W loads across all 8 steps
// (up to ~64 in flight/thread) under the 128-VGPR cap -- the MLP axis, the
// one untested lever. Fragment layouts (m89-verified):
//   A: row=lane&15, k=(lane>>4)*8+i ; B: col=lane&15, same k ;
//   D: col=lane&15, row=(lane>>4)*4+reg.
__global__ __launch_bounds__(256, 4) void banked_mfma(
    const float* __restrict__ x,      // [NTOK][IN]
    const int*   __restrict__ sel,    // [NSEL]
    const float* __restrict__ probs,  // [NSEL]
    const float* __restrict__ W,      // [NB][IN][OUT]
    const float* __restrict__ bias,   // [NB][OUT]
    ushort* __restrict__ ysel)        // [NSEL][2][OUT] bf16
{
    __shared__ __align__(16) ushort Xs[MCAP * XSTR];   // 16.9 KB
    __shared__ int   elist[ELCAP];
    __shared__ int   lcnt;
    __shared__ int   tok_s[MCAP];
    __shared__ float prob_s[MCAP];

    const int bank = blockIdx.x >> 4;
    const int tile = (blockIdx.x >> 1) & 7;   // 64-col tile
    const int half = blockIdx.x & 1;          // K half
    const int t    = threadIdx.x;

    // fused per-bank selection list (slot order free; per-e math invariant)
    if (t == 0) lcnt = 0;
    __syncthreads();
    {
        const int4 s4 = reinterpret_cast<const int4*>(sel)[t];   // t < 256 = NSEL/4
        if (s4.x == bank) { int p = atomicAdd(&lcnt, 1); if (p < ELCAP) elist[p] = 4 * t; }
        if (s4.y == bank) { int p = atomicAdd(&lcnt, 1); if (p < ELCAP) elist[p] = 4 * t + 1; }
        if (s4.z == bank) { int p = atomicAdd(&lcnt, 1); if (p < ELCAP) elist[p] = 4 * t + 2; }
        if (s4.w == bank) { int p = atomicAdd(&lcnt, 1); if (p < ELCAP) elist[p] = 4 * t + 3; }
    }
    __syncthreads();
    const int n = min(lcnt, ELCAP);
    if (n == 0) return;

    const int w   = t >> 6;        // wave = N-tile 0..3
    const int l   = t & 63;
    const int g   = l >> 4;        // lane group 0..3
    const int ln  = l & 15;
    const int col = tile * 64 + w * 16 + ln;
    const int k0b = half * KH;     // this block's K origin
    const float* wcol = W + (size_t)bank * (IN * OUT) + (size_t)k0b * OUT + col;
    const float  bcol = bias[bank * OUT + col];

    for (int c0 = 0; c0 < n; c0 += MCAP) {
        const int n_c    = min(n - c0, MCAP);
        const int mt_cnt = (n_c + 15) >> 4;

        if (t < MCAP) {
            const int idx = c0 + t;
            const int e = (idx < n) ? elist[idx] : 0;
            tok_s[t]  = e >> 1;
            prob_s[t] = (idx < n) ? probs[e] : 0.0f;
        }
        __syncthreads();

        // stage X (this half's k-range) -> LDS bf16; only occupied 16-slot
        // groups (skip slots 16..31 when n_c <= 16)
        const int nstage = mt_cnt * 16;      // 16 or 32
        #pragma unroll
        for (int k2 = 0; k2 < 8; ++k2) {
            const int oid  = t + k2 * 256;
            const int slot = oid >> 6;      // 0..31
            const int f4   = oid & 63;      // 0..63
            if (slot < nstage) {
                const float4 v = reinterpret_cast<const float4*>(
                    x + (size_t)tok_s[slot] * IN + k0b)[f4];
                uint2 b;
                b.x = cvt_pk_bf16(v.x, v.y);
                b.y = cvt_pk_bf16(v.z, v.w);
                *reinterpret_cast<uint2*>(&Xs[slot * XSTR + f4 * 4]) = b;
            }
        }
        __syncthreads();

        f32x4 accA = {0.f, 0.f, 0.f, 0.f};
        f32x4 accB = {0.f, 0.f, 0.f, 0.f};

        // barrier-free K loop: 8 steps of K=32, FULLY unrolled (MLP probe)
        #pragma unroll
        for (int ks = 0; ks < 8; ++ks) {
            const int k0 = ks * 32;
            float wf[8];
            #pragma unroll
            for (int i = 0; i < 8; ++i)
                wf[i] = wcol[(size_t)(k0 + 8 * g + i) * OUT];
            uint4 wu;
            wu.x = cvt_pk_bf16(wf[0], wf[1]);
            wu.y = cvt_pk_bf16(wf[2], wf[3]);
            wu.z = cvt_pk_bf16(wf[4], wf[5]);
            wu.w = cvt_pk_bf16(wf[6], wf[7]);
            const bf16x8 bfrag = __builtin_bit_cast(bf16x8, wu);

            const bf16x8 a0 = *reinterpret_cast<const bf16x8*>(
                &Xs[(size_t)ln * XSTR + k0 + 8 * g]);
            accA = __builtin_amdgcn_mfma_f32_16x16x32_bf16(a0, bfrag, accA, 0, 0, 0);
            if (mt_cnt > 1) {
                const bf16x8 a1 = *reinterpret_cast<const bf16x8*>(
                    &Xs[(size_t)(16 + ln) * XSTR + k0 + 8 * g]);
                accB = __builtin_amdgcn_mfma_f32_16x16x32_bf16(a1, bfrag, accB, 0, 0, 0);
            }
        }

        // epilogue: D row=(l>>4)*4+r, col=ln; bias folded in half 0; bf16 store
        #pragma unroll
        for (int mt = 0; mt < 2; ++mt) {
            if (mt == 1 && mt_cnt < 2) break;
            const f32x4 a = (mt == 0) ? accA : accB;
            #pragma unroll
            for (int r = 0; r < 4; ++r) {
                const int slot = mt * 16 + 4 * g + r;
                if (slot < n_c) {
                    const float p = prob_s[slot];
                    const int e = elist[c0 + slot];
                    const float v = (half == 0) ? (a[r] + bcol) * p : a[r] * p;
                    ysel[((size_t)e * 2 + half) * OUT + col] =
                        (ushort)(cvt_pk_bf16(v, 0.0f) & 0xffffu);
                }
            }
        }
        __syncthreads();   // before restaging next pass
    }
}

// out[t] = sum over (k=2 selections) x (2 K-halves); ysel is bf16
__global__ __launch_bounds__(256) void combine(const ushort* __restrict__ ysel,
                                               float* __restrict__ out) {
    const int i  = blockIdx.x * 256 + threadIdx.x;   // 8-col unit, 32768 total
    const int tk = i >> 6;          // token
    const int c8 = i & 63;          // 8-col group
    const uint4* yb = reinterpret_cast<const uint4*>(ysel);   // 8 bf16 / uint4
    const size_t base = (size_t)(2 * tk) * 2 * (OUT / 8);     // [e][half] rows
    const uint4 a = yb[base + c8];
    const uint4 b = yb[base + 64 + c8];
    const uint4 c = yb[base + 128 + c8];
    const uint4 d = yb[base + 192 + c8];

    float r[8];
    #pragma unroll
    for (int j = 0; j < 4; ++j) {
        const uint32_t ua = (&a.x)[j], ub = (&b.x)[j], uc = (&c.x)[j], ud = (&d.x)[j];
        r[2 * j] = __builtin_bit_cast(float, ua << 16) + __builtin_bit_cast(float, ub << 16)
                 + __builtin_bit_cast(float, uc << 16) + __builtin_bit_cast(float, ud << 16);
        r[2 * j + 1] = __builtin_bit_cast(float, ua & 0xffff0000u)
                     + __builtin_bit_cast(float, ub & 0xffff0000u)
                     + __builtin_bit_cast(float, uc & 0xffff0000u)
                     + __builtin_bit_cast(float, ud & 0xffff0000u);
    }
    float4* o4 = reinterpret_cast<float4*>(out + (size_t)tk * OUT + c8 * 8);
    o4[0] = make_float4(r[0], r[1], r[2], r[3]);
    o4[1] = make_float4(r[4], r[5], r[6], r[7]);
}

extern "C" void kernel_launch(void* const* d_in, const int* in_sizes, int n_in,
                              void* d_out, int out_size, void* d_ws, size_t ws_size,
                              hipStream_t stream) {
    const float* x     = (const float*)d_in[0];
    const int*   sel   = (const int*)d_in[1];
    const float* probs = (const float*)d_in[2];
    const float* W     = (const float*)d_in[3];
    const float* bias  = (const float*)d_in[4];
    float*  out  = (float*)d_out;
    ushort* ysel = (ushort*)d_ws;    // [NSEL][2][OUT] bf16 = 2 MB

    banked_mfma<<<NB * 8 * 2, 256, 0, stream>>>(x, sel, probs, W, bias, ysel);
    combine<<<(NTOK * OUT / 8) / 256, 256, 0, stream>>>(ysel, out);
}

// Round 20
// 21.051 us; speedup vs baseline: 1.8576x; 1.8576x over previous
//
#include <hip/hip_runtime.h>
#include <stdint.h>

#define NB    64
#define IN    512
#define OUT   512
#define NTOK  512
#define NSEL  1024      // NTOK*K
#define MCAP  32        // token slots per pass (binomial mean 16, sd 4 -> 1 pass)
#define KH    256       // K rows per block (half)
#define XSTR  264       // bf16 per X row (256 + 8 pad; dword-stride 132%32=4)
#define ELCAP 96

typedef __attribute__((ext_vector_type(8))) short bf16x8;
typedef __attribute__((ext_vector_type(4))) float f32x4;

__device__ __forceinline__ ushort f2bf(float f) {   // RNE f32->bf16 (verified R9)
    uint32_t u = __builtin_bit_cast(uint32_t, f);
    u += 0x7fffu + ((u >> 16) & 1u);
    return (ushort)(u >> 16);
}

// Block = (bank, 64-col tile, 256-row K-half): 1024 blocks, 256 thr = 4 waves.
// Measured-best configuration (R12, 21.0 us). Wave w = N-tile of 16 cols.
// MFMA accumulates K=256 (8 steps of 32). A (X) staged in LDS bf16 (all 32
// slots); fragment layouts (m89-verified): A: row=lane&15, k=(lane>>4)*8+i ;
//   B: col=lane&15, same k ; D: col=lane&15, row=(lane>>4)*4+reg.
// B (W) loaded per-lane scalar from global (line-disjoint per block).
// K-loop barrier-free, unroll 2 (full unroll spills -- R19). No atomics.
__global__ __launch_bounds__(256) void banked_mfma(
    const float* __restrict__ x,      // [NTOK][IN]
    const int*   __restrict__ sel,    // [NSEL]
    const float* __restrict__ probs,  // [NSEL]
    const float* __restrict__ W,      // [NB][IN][OUT]
    const float* __restrict__ bias,   // [NB][OUT]
    float* __restrict__ ysel)         // [NSEL][2][OUT]
{
    __shared__ __align__(16) ushort Xs[MCAP * XSTR];   // 16.9 KB
    __shared__ int   elist[ELCAP];
    __shared__ int   lcnt;
    __shared__ int   tok_s[MCAP];
    __shared__ float prob_s[MCAP];

    const int bank = blockIdx.x >> 4;
    const int tile = (blockIdx.x >> 1) & 7;   // 64-col tile
    const int half = blockIdx.x & 1;          // K half
    const int t    = threadIdx.x;

    // fused per-bank selection list (slot order free; per-e math invariant)
    if (t == 0) lcnt = 0;
    __syncthreads();
    {
        const int4 s4 = reinterpret_cast<const int4*>(sel)[t];   // t < 256 = NSEL/4
        if (s4.x == bank) { int p = atomicAdd(&lcnt, 1); if (p < ELCAP) elist[p] = 4 * t; }
        if (s4.y == bank) { int p = atomicAdd(&lcnt, 1); if (p < ELCAP) elist[p] = 4 * t + 1; }
        if (s4.z == bank) { int p = atomicAdd(&lcnt, 1); if (p < ELCAP) elist[p] = 4 * t + 2; }
        if (s4.w == bank) { int p = atomicAdd(&lcnt, 1); if (p < ELCAP) elist[p] = 4 * t + 3; }
    }
    __syncthreads();
    const int n = min(lcnt, ELCAP);
    if (n == 0) return;

    const int w   = t >> 6;        // wave = N-tile 0..3
    const int l   = t & 63;
    const int g   = l >> 4;        // lane group 0..3
    const int ln  = l & 15;
    const int col = tile * 64 + w * 16 + ln;
    const int k0b = half * KH;     // this block's K origin
    const float* wcol = W + (size_t)bank * (IN * OUT) + (size_t)k0b * OUT + col;
    const float  bcol = bias[bank * OUT + col];

    for (int c0 = 0; c0 < n; c0 += MCAP) {
        const int n_c    = min(n - c0, MCAP);
        const int mt_cnt = (n_c + 15) >> 4;

        if (t < MCAP) {
            const int idx = c0 + t;
            const int e = (idx < n) ? elist[idx] : 0;
            tok_s[t]  = e >> 1;
            prob_s[t] = (idx < n) ? probs[e] : 0.0f;
        }
        __syncthreads();

        // stage X (this half's k-range) -> LDS bf16 for ALL 32 slots:
        // 32 slots x 64 ushort4 = 2048 stores, 8 per thread
        #pragma unroll
        for (int k2 = 0; k2 < 8; ++k2) {
            const int oid  = t + k2 * 256;
            const int slot = oid >> 6;      // 0..31
            const int f4   = oid & 63;      // 0..63
            const float4 v = reinterpret_cast<const float4*>(
                x + (size_t)tok_s[slot] * IN + k0b)[f4];
            ushort4 b;
            b.x = f2bf(v.x); b.y = f2bf(v.y); b.z = f2bf(v.z); b.w = f2bf(v.w);
            *reinterpret_cast<ushort4*>(&Xs[slot * XSTR + f4 * 4]) = b;
        }
        __syncthreads();

        f32x4 accA = {0.f, 0.f, 0.f, 0.f};
        f32x4 accB = {0.f, 0.f, 0.f, 0.f};

        // barrier-free K loop: 8 steps of K=32
        #pragma unroll 2
        for (int ks = 0; ks < 8; ++ks) {
            const int k0 = ks * 32;
            float wf[8];
            #pragma unroll
            for (int i = 0; i < 8; ++i)
                wf[i] = wcol[(size_t)(k0 + 8 * g + i) * OUT];
            bf16x8 bfrag;
            #pragma unroll
            for (int i = 0; i < 8; ++i) bfrag[i] = (short)f2bf(wf[i]);

            const bf16x8 a0 = *reinterpret_cast<const bf16x8*>(
                &Xs[(size_t)ln * XSTR + k0 + 8 * g]);
            accA = __builtin_amdgcn_mfma_f32_16x16x32_bf16(a0, bfrag, accA, 0, 0, 0);
            if (mt_cnt > 1) {
                const bf16x8 a1 = *reinterpret_cast<const bf16x8*>(
                    &Xs[(size_t)(16 + ln) * XSTR + k0 + 8 * g]);
                accB = __builtin_amdgcn_mfma_f32_16x16x32_bf16(a1, bfrag, accB, 0, 0, 0);
            }
        }

        // epilogue: D row=(l>>4)*4+r, col=ln; bias folded in half 0 only
        #pragma unroll
        for (int mt = 0; mt < 2; ++mt) {
            if (mt == 1 && mt_cnt < 2) break;
            const f32x4 a = (mt == 0) ? accA : accB;
            #pragma unroll
            for (int r = 0; r < 4; ++r) {
                const int slot = mt * 16 + 4 * g + r;
                if (slot < n_c) {
                    const float p = prob_s[slot];
                    const int e = elist[c0 + slot];
                    const float v = (half == 0) ? (a[r] + bcol) * p : a[r] * p;
                    ysel[((size_t)e * 2 + half) * OUT + col] = v;
                }
            }
        }
        __syncthreads();   // before restaging next pass
    }
}

// out[t] = sum over (k=2 selections) x (2 K-halves)
__global__ __launch_bounds__(256) void combine(const float* __restrict__ ysel,
                                               float* __restrict__ out) {
    const int i  = blockIdx.x * 256 + threadIdx.x;   // float4 index, 65536
    const int tk = i >> 7;
    const int c  = i & 127;
    const float4* y4 = reinterpret_cast<const float4*>(ysel);
    const size_t b0 = (size_t)(2 * tk) * 2 * 128;    // [e][half][128 f4]
    const float4 a  = y4[b0 + c];
    const float4 b  = y4[b0 + 128 + c];
    const float4 cc = y4[b0 + 256 + c];
    const float4 d  = y4[b0 + 384 + c];
    float4 r;
    r.x = (a.x + b.x) + (cc.x + d.x);
    r.y = (a.y + b.y) + (cc.y + d.y);
    r.z = (a.z + b.z) + (cc.z + d.z);
    r.w = (a.w + b.w) + (cc.w + d.w);
    reinterpret_cast<float4*>(out)[i] = r;
}

extern "C" void kernel_launch(void* const* d_in, const int* in_sizes, int n_in,
                              void* d_out, int out_size, void* d_ws, size_t ws_size,
                              hipStream_t stream) {
    const float* x     = (const float*)d_in[0];
    const int*   sel   = (const int*)d_in[1];
    const float* probs = (const float*)d_in[2];
    const float* W     = (const float*)d_in[3];
    const float* bias  = (const float*)d_in[4];
    float* out  = (float*)d_out;
    float* ysel = (float*)d_ws;     // [NSEL][2][OUT] = 4 MB

    banked_mfma<<<NB * 8 * 2, 256, 0, stream>>>(x, sel, probs, W, bias, ysel);
    combine<<<(NTOK * OUT / 4) / 256, 256, 0, stream>>>(ysel, out);
}